// Round 10
// baseline (21382.968 us; speedup 1.0000x reference)
//
#include <hip/hip_runtime.h>
#include <math.h>

// ---------------------------------------------------------------------------
// LSTM-CRF (B=64,T=512,E=256,H=256,K=32,V=50000), all f32.
// Recurrence: BATCH-PARALLEL, sync-free. WG = (dir, batch-pair), 512 thr.
// Thread = (u, k-half j). Each thread accumulates BOTH batches over its
// 128 k's (weight dedup), partials exchanged via LDS. 16-deep explicit
// weight-load pipeline; weights stream from per-XCD L2 (1 MB/WG/step).
// Layouts (row-major):
//   xg  [d*4096 + ls*64 + b][1024]   (per-chunk, reused; em aliases this)
//   out [t*64 + b][512]              (col = d*256 + u)
//   em  [t*64 + b][32]
//   wq  [d][k(256)][u(256)][g(4)]    (per-layer, rebuilt between layers)
// ---------------------------------------------------------------------------

constexpr int TLEN = 512, CS = 64, NCH = 8;

constexpr size_t N_OUT  = (size_t)TLEN * 64 * 512;      // 16,777,216
constexpr size_t O_OUT0 = 0;
constexpr size_t O_OUT1 = N_OUT;
constexpr size_t O_XG   = 2 * N_OUT;
constexpr size_t N_XG   = (size_t)2 * CS * 64 * 1024;   // 8,388,608
constexpr size_t O_EM   = O_XG;                         // alias: xg dead when em live
constexpr size_t O_WQ   = O_XG + N_XG;
constexpr size_t N_WQ   = (size_t)2 * 256 * 256 * 4;    // 524,288 (one layer)
constexpr size_t O_CST  = O_WQ + N_WQ;
constexpr size_t N_CST  = (size_t)2 * 2 * 64 * 256;     // 65,536 (2 layers)
constexpr size_t WS_FLOATS = O_CST + N_CST;             // 42,532,864 ~ 170.1 MB

// ---------------------------------------------------------------------- init
__global__ void initz(float* dout) { if (threadIdx.x == 0) dout[0] = 0.f; }

__global__ void ws_too_small_k(float* dout, int n) {
  int i = blockIdx.x * 256 + threadIdx.x;
  if (i < n) dout[i] = 1e30f;  // clean diagnostic failure, no fault
}

// ------------------------------------------------------------------ prep_w
// wq[d][k][u][g] = whh_d[(g*256+u)*256 + k]; one float4 store per thread.
__global__ __launch_bounds__(256)
void prep_w(const float* __restrict__ whhf, const float* __restrict__ whhb,
            float* __restrict__ wq) {
  const int k = blockIdx.x & 255, d = blockIdx.x >> 8, u = threadIdx.x;
  const float* W = d ? whhb : whhf;
  float4 v;
  v.x = W[(size_t)(0   + u) * 256 + k];
  v.y = W[(size_t)(256 + u) * 256 + k];
  v.z = W[(size_t)(512 + u) * 256 + k];
  v.w = W[(size_t)(768 + u) * 256 + k];
  reinterpret_cast<float4*>(wq)[(size_t)d * 65536 + k * 256 + u] = v;
}

// -------------------------------------------------------------------- GEMM
// C = A @ W^T + bias, C row-major.
// MODE 0: A-rows gathered from emb via ids (layer-0 xg, K=256, BN=128)
// MODE 1: A = out0 row-major, rows t*64+b (layer-1 xg, K=512, BN=128)
// MODE 2: A = out1 row-major, rows = m  (emissions, K=512, BN=32)
template <int KTOT, int BN, int MODE>
__global__ __launch_bounds__(256)
void gemm_k(const float* __restrict__ A, const int* __restrict__ ids,
            const float* __restrict__ Wf, const float* __restrict__ Wb,
            const float* __restrict__ bf, const float* __restrict__ bb,
            float* __restrict__ C, int s0) {
  constexpr int BK = 16;
  constexpr int NC = (BN == 128) ? 8 : 2;  // cols per thread
  __shared__ float As[BK][132];
  __shared__ float Bs[BK][BN + 4];
  const int tid = threadIdx.x;
  const int m0 = blockIdx.x * 128, n0 = blockIdx.y * BN, d = blockIdx.z;
  const float* W = (MODE < 2 && d) ? Wb : Wf;
  const float* bias = (MODE < 2 && d) ? bb : bf;
  const int mg = tid & 15, ng = tid >> 4;
  const int rb = tid >> 2;            // 0..63
  const int kq = (tid & 3) << 2;      // 0,4,8,12

  int arow[2];
  #pragma unroll
  for (int p = 0; p < 2; ++p) {
    if (MODE == 2) {
      arow[p] = m0 + p * 64 + rb;
    } else {
      int s = s0 + (m0 >> 6) + p;
      int t = d ? (TLEN - 1 - s) : s;
      arow[p] = (MODE == 0) ? ids[rb * TLEN + t] : (t * 64 + rb);
    }
  }

  float acc[8][NC];
  #pragma unroll
  for (int i = 0; i < 8; ++i)
    #pragma unroll
    for (int jj = 0; jj < NC; ++jj) acc[i][jj] = 0.f;

  for (int kt = 0; kt < KTOT; kt += BK) {
    #pragma unroll
    for (int p = 0; p < 2; ++p) {
      float4 v = *reinterpret_cast<const float4*>(A + (size_t)arow[p] * KTOT + kt + kq);
      int r = p * 64 + rb;
      As[kq + 0][r] = v.x; As[kq + 1][r] = v.y;
      As[kq + 2][r] = v.z; As[kq + 3][r] = v.w;
    }
    #pragma unroll
    for (int p = 0; p < 2; ++p) {
      int r = p * 64 + rb;
      if (BN == 128 || (p == 0 && rb < BN)) {
        float4 v = *reinterpret_cast<const float4*>(W + (size_t)(n0 + r) * KTOT + kt + kq);
        Bs[kq + 0][r] = v.x; Bs[kq + 1][r] = v.y;
        Bs[kq + 2][r] = v.z; Bs[kq + 3][r] = v.w;
      }
    }
    __syncthreads();
    #pragma unroll
    for (int k = 0; k < BK; ++k) {
      float a[8];
      #pragma unroll
      for (int i = 0; i < 8; ++i) a[i] = As[k][i * 16 + mg];
      if (BN == 128) {
        float w[8];
        float4 w0 = *reinterpret_cast<const float4*>(&Bs[k][ng * 8]);
        float4 w1 = *reinterpret_cast<const float4*>(&Bs[k][ng * 8 + 4]);
        w[0] = w0.x; w[1] = w0.y; w[2] = w0.z; w[3] = w0.w;
        w[4] = w1.x; w[5] = w1.y; w[6] = w1.z; w[7] = w1.w;
        #pragma unroll
        for (int i = 0; i < 8; ++i)
          #pragma unroll
          for (int jj = 0; jj < 8; ++jj) acc[i][jj] += a[i] * w[jj];
      } else {
        float w0 = Bs[k][ng * 2], w1 = Bs[k][ng * 2 + 1];
        #pragma unroll
        for (int i = 0; i < 8; ++i) {
          acc[i][0] += a[i] * w0;
          acc[i][1] += a[i] * w1;
        }
      }
    }
    __syncthreads();
  }

  if (BN == 128) {
    float bv[8];
    #pragma unroll
    for (int jj = 0; jj < 8; ++jj) bv[jj] = bias[n0 + ng * 8 + jj];
    #pragma unroll
    for (int i = 0; i < 8; ++i) {
      const int ml = i * 16 + mg;
      float* cp = C + ((size_t)d * 4096 + m0 + ml) * 1024 + n0 + ng * 8;
      float4 o0, o1;
      o0.x = acc[i][0] + bv[0]; o0.y = acc[i][1] + bv[1];
      o0.z = acc[i][2] + bv[2]; o0.w = acc[i][3] + bv[3];
      o1.x = acc[i][4] + bv[4]; o1.y = acc[i][5] + bv[5];
      o1.z = acc[i][6] + bv[6]; o1.w = acc[i][7] + bv[7];
      reinterpret_cast<float4*>(cp)[0] = o0;
      reinterpret_cast<float4*>(cp)[1] = o1;
    }
  } else {
    const float b0 = bias[ng * 2], b1 = bias[ng * 2 + 1];
    #pragma unroll
    for (int i = 0; i < 8; ++i) {
      const int ml = i * 16 + mg;
      float* cp = C + (size_t)(m0 + ml) * 32 + ng * 2;
      cp[0] = acc[i][0] + b0;
      cp[1] = acc[i][1] + b1;
    }
  }
}

// ------------------------------------------------------------- LSTM recurrence
// grid = 64 x 512 thr: d = bid>>5, batch-pair = bid&31.
// thread = (u = tid&255, j = tid>>8); j = k-half AND finalized batch.
// Each thread accumulates BOTH batches over k in [128j, 128j+128);
// partials for the other batch exchanged via LDS red[][][].
static __device__ __forceinline__ float sigm(float x) { return 1.f / (1.f + expf(-x)); }

__global__ __launch_bounds__(512, 2)
void lstm_bp(const float* __restrict__ xg, const float* __restrict__ wq,
             float* __restrict__ out, float* __restrict__ cst, int s0) {
  const int d = blockIdx.x >> 5;
  const int bp = blockIdx.x & 31;
  const int u = threadIdx.x & 255;
  const int j = threadIdx.x >> 8;        // wave-uniform (waves 0-3: 0, 4-7: 1)
  const int b = bp * 2 + j;              // batch this thread finalizes
  const int kbase = j * 128;             // this thread's k-half
  const float4* wp = reinterpret_cast<const float4*>(wq) + (size_t)d * 65536 + u;
  float* cptr = cst + ((size_t)d * 64 + b) * 256 + u;
  __shared__ float hs[2][2][256];        // [parity][batch-in-pair][unit]
  __shared__ float red[4][2][256];       // [gate][writer-half][unit]
  float c;
  if (s0 == 0) {
    c = 0.f;
    hs[0][j][u] = 0.f;
  } else {
    c = *cptr;
    const int tp = d ? (TLEN - s0) : (s0 - 1);
    hs[0][j][u] = out[((size_t)tp * 64 + b) * 512 + d * 256 + u];
  }
  __syncthreads();
  int p = 0;
  for (int ls = 0; ls < CS; ++ls) {
    const int s = s0 + ls;
    const int t = d ? (TLEN - 1 - s) : s;
    const size_t xb = (((size_t)d * CS + ls) * 64 + b) * 1024;
    const float xi  = xg[xb + u];          // issued early, used after k-loop
    const float xf  = xg[xb + 256 + u];
    const float xgv = xg[xb + 512 + u];
    const float xo  = xg[xb + 768 + u];
    float p0[4] = {0.f, 0.f, 0.f, 0.f};    // partials batch b0 (my k-half)
    float p1[4] = {0.f, 0.f, 0.f, 0.f};    // partials batch b1
    const float4* h0p = reinterpret_cast<const float4*>(&hs[p][0][kbase]);
    const float4* h1p = reinterpret_cast<const float4*>(&hs[p][1][kbase]);
    #pragma unroll
    for (int kk = 0; kk < 128; kk += 16) {
      float4 w[16];                        // 16-deep load pipeline (64 VGPR)
      #pragma unroll
      for (int i = 0; i < 16; ++i) w[i] = wp[(size_t)(kbase + kk + i) * 256];
      #pragma unroll
      for (int q4 = 0; q4 < 4; ++q4) {
        const float4 h0 = h0p[(kk >> 2) + q4];   // wave-broadcast LDS reads
        const float4 h1 = h1p[(kk >> 2) + q4];
        #pragma unroll
        for (int q = 0; q < 4; ++q) {
          const float4 wv = w[q4 * 4 + q];
          const float e0 = (q == 0) ? h0.x : (q == 1) ? h0.y : (q == 2) ? h0.z : h0.w;
          const float e1 = (q == 0) ? h1.x : (q == 1) ? h1.y : (q == 2) ? h1.z : h1.w;
          p0[0] = fmaf(e0, wv.x, p0[0]);
          p0[1] = fmaf(e0, wv.y, p0[1]);
          p0[2] = fmaf(e0, wv.z, p0[2]);
          p0[3] = fmaf(e0, wv.w, p0[3]);
          p1[0] = fmaf(e1, wv.x, p1[0]);
          p1[1] = fmaf(e1, wv.y, p1[1]);
          p1[2] = fmaf(e1, wv.z, p1[2]);
          p1[3] = fmaf(e1, wv.w, p1[3]);
        }
      }
    }
    // exchange other-batch partials (scalar ternaries: j is wave-uniform)
    #pragma unroll
    for (int i = 0; i < 4; ++i) red[i][j][u] = j ? p0[i] : p1[i];
    __syncthreads();
    const float ai = (j ? p1[0] : p0[0]) + red[0][j ^ 1][u];
    const float af = (j ? p1[1] : p0[1]) + red[1][j ^ 1][u];
    const float ag = (j ? p1[2] : p0[2]) + red[2][j ^ 1][u];
    const float ao = (j ? p1[3] : p0[3]) + red[3][j ^ 1][u];
    const float gi = sigm(xi + ai), gf = sigm(xf + af);
    const float gc = tanhf(xgv + ag), go = sigm(xo + ao);
    c = gf * c + gi * gc;
    const float h = go * tanhf(c);
    hs[p ^ 1][j][u] = h;
    out[((size_t)t * 64 + b) * 512 + d * 256 + u] = h;
    __syncthreads();   // hs[p^1] complete & red reads done before next step
    p ^= 1;
  }
  *cptr = c;
}

// ------------------------------------------------------- CRF loss + Viterbi
// grid=128, 64 thr: blocks 0..63 loss(batch b), 64..127 viterbi(batch b).
__global__ __launch_bounds__(64)
void crf_k(const float* __restrict__ em, const int* __restrict__ labels,
           const float* __restrict__ cs, const float* __restrict__ ce,
           const float* __restrict__ ct, float* __restrict__ dout) {
  __shared__ float trs[32 * 32];
  __shared__ float as_[32];
  __shared__ unsigned char bp[511 * 32];
  const int b = blockIdx.x & 63;
  const bool vit = blockIdx.x >= 64;
  const int lane = threadIdx.x;
  for (int i = lane; i < 1024; i += 64) trs[i] = ct[i];
  __syncthreads();
  const int j = lane & 31, half = lane >> 5, i0 = half * 16;

  if (!vit) {
    float part = 0.f;
    for (int tt = lane; tt < TLEN; tt += 64) {
      int lab = labels[b * TLEN + tt];
      part += em[((size_t)tt * 64 + b) * 32 + lab];
      if (tt) part += trs[labels[b * TLEN + tt - 1] * 32 + lab];
    }
    for (int o = 32; o > 0; o >>= 1) part += __shfl_down(part, o);
    float num = part;  // lane 0
    if (lane == 0) num += cs[labels[b * TLEN]] + ce[labels[b * TLEN + TLEN - 1]];
    if (lane < 32) as_[j] = cs[j] + em[(size_t)b * 32 + j];
    __syncthreads();
    for (int t = 1; t < TLEN; ++t) {
      float m = -1e30f;
      #pragma unroll
      for (int ii = 0; ii < 16; ++ii)
        m = fmaxf(m, as_[i0 + ii] + trs[(i0 + ii) * 32 + j]);
      float s = 0.f;
      #pragma unroll
      for (int ii = 0; ii < 16; ++ii)
        s += expf(as_[i0 + ii] + trs[(i0 + ii) * 32 + j] - m);
      float om = __shfl_xor(m, 32), os = __shfl_xor(s, 32);
      float M = fmaxf(m, om);
      s = s * expf(m - M) + os * expf(om - M);
      float na = M + logf(s) + em[((size_t)t * 64 + b) * 32 + j];
      __syncthreads();
      if (half == 0) as_[j] = na;
      __syncthreads();
    }
    float v = (lane < 32) ? as_[j] + ce[j] : -1e30f;
    float m = v;
    for (int o = 32; o > 0; o >>= 1) m = fmaxf(m, __shfl_xor(m, o));
    float s = (lane < 32) ? expf(v - m) : 0.f;
    for (int o = 32; o > 0; o >>= 1) s += __shfl_xor(s, o);
    if (lane == 0) atomicAdd(dout, -(num - (m + logf(s))));
  } else {
    if (lane < 32) as_[j] = cs[j] + em[(size_t)b * 32 + j];
    __syncthreads();
    for (int t = 1; t < TLEN; ++t) {
      float m = -1e30f; int am = 0;
      #pragma unroll
      for (int ii = 0; ii < 16; ++ii) {
        float v = as_[i0 + ii] + trs[(i0 + ii) * 32 + j];
        if (v > m) { m = v; am = i0 + ii; }
      }
      float om = __shfl_xor(m, 32); int oam = __shfl_xor(am, 32);
      float M; int AM;
      if (half == 0) { if (om > m) { M = om; AM = oam; } else { M = m; AM = am; } }
      else           { if (m > om) { M = m; AM = am; } else { M = om; AM = oam; } }
      float na = M + em[((size_t)t * 64 + b) * 32 + j];
      if (half == 0) bp[(t - 1) * 32 + j] = (unsigned char)AM;
      __syncthreads();
      if (half == 0) as_[j] = na;
      __syncthreads();
    }
    float v = (lane < 32) ? as_[j] + ce[j] : -1e30f;
    int aj = (lane < 32) ? j : 0;
    #pragma unroll
    for (int o = 1; o < 64; o <<= 1) {
      float ov = __shfl_xor(v, o); int oa = __shfl_xor(aj, o);
      if (ov > v || (ov == v && oa < aj)) { v = ov; aj = oa; }
    }
    if (lane == 0) {
      int cur = aj;
      dout[1 + b * TLEN + TLEN - 1] = (float)cur;
      for (int t = TLEN - 1; t >= 1; --t) {
        cur = bp[(t - 1) * 32 + cur];
        dout[1 + b * TLEN + t - 1] = (float)cur;
      }
    }
  }
}

// --------------------------------------------------------------------- launch
extern "C" void kernel_launch(void* const* d_in, const int* in_sizes, int n_in,
                              void* d_out, int out_size, void* d_ws, size_t ws_size,
                              hipStream_t stream) {
  (void)in_sizes; (void)n_in;
  float* dout = (float*)d_out;
  if (ws_size < WS_FLOATS * sizeof(float)) {  // diagnostic, not a fault
    ws_too_small_k<<<(out_size + 255) / 256, 256, 0, stream>>>(dout, out_size);
    return;
  }
  const int* ids    = (const int*)d_in[0];
  const int* labels = (const int*)d_in[1];
  const float* emb  = (const float*)d_in[3];
  const float* wih0f = (const float*)d_in[4],  *whh0f = (const float*)d_in[5],  *b0f = (const float*)d_in[6];
  const float* wih0b = (const float*)d_in[7],  *whh0b = (const float*)d_in[8],  *b0b = (const float*)d_in[9];
  const float* wih1f = (const float*)d_in[10], *whh1f = (const float*)d_in[11], *b1f = (const float*)d_in[12];
  const float* wih1b = (const float*)d_in[13], *whh1b = (const float*)d_in[14], *b1b = (const float*)d_in[15];
  const float* w_out = (const float*)d_in[16], *b_out = (const float*)d_in[17];
  const float* c_s = (const float*)d_in[18], *c_e = (const float*)d_in[19], *c_t = (const float*)d_in[20];
  float* ws   = (float*)d_ws;
  float* out0 = ws + O_OUT0;
  float* out1 = ws + O_OUT1;
  float* xg   = ws + O_XG;
  float* em   = ws + O_EM;    // aliases xg (xg dead once recurrences finish)
  float* wq   = ws + O_WQ;
  float* cst  = ws + O_CST;

  initz<<<1, 64, 0, stream>>>(dout);

  prep_w<<<512, 256, 0, stream>>>(whh0f, whh0b, wq);
  for (int k = 0; k < NCH; ++k) {
    gemm_k<256, 128, 0><<<dim3(32, 8, 2), 256, 0, stream>>>(
        emb, ids, wih0f, wih0b, b0f, b0b, xg, k * CS);
    lstm_bp<<<64, 512, 0, stream>>>(xg, wq, out0, cst, k * CS);
  }

  prep_w<<<512, 256, 0, stream>>>(whh1f, whh1b, wq);
  for (int k = 0; k < NCH; ++k) {
    gemm_k<512, 128, 1><<<dim3(32, 8, 2), 256, 0, stream>>>(
        out0, nullptr, wih1f, wih1b, b1f, b1b, xg, k * CS);
    lstm_bp<<<64, 512, 0, stream>>>(xg, wq, out1, cst + 32768, k * CS);
  }

  gemm_k<512, 32, 2><<<dim3(256, 1, 1), 256, 0, stream>>>(
      out1, nullptr, w_out, nullptr, b_out, nullptr, em, 0);
  crf_k<<<128, 64, 0, stream>>>(em, labels, c_s, c_e, c_t, dout);
}